// Round 5
// baseline (175.117 us; speedup 1.0000x reference)
//
#include <hip/hip_runtime.h>
#include <math.h>

typedef __attribute__((ext_vector_type(4))) float f32x4;
typedef __attribute__((ext_vector_type(8))) short bf16x8;

namespace {
constexpr int kB = 2;
constexpr int kS = 1024;
constexpr int kD = 128;
constexpr int kQT = 64;   // q rows per block (16 per wave)
constexpr int kKT = 64;   // kv rows per tile
constexpr int kNT = kS / kQT;  // 16 q-tiles
constexpr float kScale = 0.08838834764831845f;   // 1/sqrt(128)
constexpr float kLog2e = 1.4426950408889634f;
constexpr float kFreqC = 0.20503692777194262f;   // ln(500000)/64
constexpr int kKPad = 136;  // fallback kernel pads
constexpr int kVPad = 72;

// workspace layout (bytes)
constexpr size_t kTabOff = 0;                       // float2[1024*64] = 512 KB
constexpr size_t kKOff = 512 * 1024;                // bf16 [2][8][1024][128]
constexpr size_t kVOff = kKOff + 4194304;           // bf16 [2][8][128][1024]
constexpr size_t kWsNeed = kVOff + 4194304;         // ~8.9 MB
}

#define VMCNT(n) asm volatile("s_waitcnt vmcnt(" #n ")" ::: "memory")

__device__ inline short f2bf(float f) {  // RNE float->bf16
  union { float f; unsigned u; } c{f};
  unsigned r = c.u + 0x7fffu + ((c.u >> 16) & 1u);
  return (short)(r >> 16);
}

__device__ inline void gload16(const void* g, void* l) {
  __builtin_amdgcn_global_load_lds(
      (const __attribute__((address_space(1))) void*)g,
      (__attribute__((address_space(3))) void*)l, 16, 0, 0);
}

// tab[pos*64 + j] = (cos(pos*f_j), sin(pos*f_j))
__global__ __launch_bounds__(256) void rope_table_k(float2* __restrict__ tab) {
  int t = blockIdx.x * 256 + threadIdx.x;  // 1024*64
  int pos = t >> 6, j = t & 63;
  float ang = (float)pos * expf(-(float)j * kFreqC);
  float sn, cs;
  sincosf(ang, &sn, &cs);
  tab[t] = make_float2(cs, sn);
}

// Prepass: RoPE K into bf16, layout [b][h][s][d]. One thread = 4 pairs.
__global__ __launch_bounds__(256) void rope_k_only(
    const float* __restrict__ k, const float2* __restrict__ tab,
    short* __restrict__ Kp) {
  int t2 = blockIdx.x * 256 + threadIdx.x;  // 262144
  int j = (t2 & 15) * 4;
  int h = (t2 >> 4) & 7;
  int s = (t2 >> 7) & 1023;
  int b = t2 >> 17;
  size_t sidx = ((size_t)b * 1024 + s) * 1024 + h * 128 + j;
  size_t didx = (((size_t)b * 8 + h) * 1024 + s) * 128 + j;
  float4 x1 = *(const float4*)&k[sidx];
  float4 x2 = *(const float4*)&k[sidx + 64];
  float4 t0 = *(const float4*)&tab[s * 64 + j];      // c0 s0 c1 s1
  float4 t1 = *(const float4*)&tab[s * 64 + j + 2];  // c2 s2 c3 s3
  short4 y1, y2;
  y1.x = f2bf(x1.x * t0.x - x2.x * t0.y);
  y2.x = f2bf(x1.x * t0.y + x2.x * t0.x);
  y1.y = f2bf(x1.y * t0.z - x2.y * t0.w);
  y2.y = f2bf(x1.y * t0.w + x2.y * t0.z);
  y1.z = f2bf(x1.z * t1.x - x2.z * t1.y);
  y2.z = f2bf(x1.z * t1.y + x2.z * t1.x);
  y1.w = f2bf(x1.w * t1.z - x2.w * t1.w);
  y2.w = f2bf(x1.w * t1.w + x2.w * t1.z);
  *(short4*)&Kp[didx] = y1;
  *(short4*)&Kp[didx + 64] = y2;
}

// Prepass: V transpose to [b][hkv][d][s] bf16. Block: 64s x 64d tile.
__global__ __launch_bounds__(256) void v_tr_k(const float* __restrict__ v,
                                              short* __restrict__ Vp) {
  __shared__ float Tl[64][68];
  int blk = blockIdx.x;
  int bh = blk >> 5;            // 0..15 = b*8+h
  int rem = blk & 31;
  int s0 = (rem >> 1) * 64;
  int d0 = (rem & 1) * 64;
  int t = threadIdx.x;
#pragma unroll
  for (int i = 0; i < 4; ++i) {
    int srow = i * 16 + (t >> 4);
    int scol = (t & 15) * 4;
    float4 x = *(const float4*)&v[((size_t)(bh >> 3) * 1024 + s0 + srow) * 1024 +
                                  (bh & 7) * 128 + d0 + scol];
    *(float4*)&Tl[srow][scol] = x;
  }
  __syncthreads();
#pragma unroll
  for (int i = 0; i < 4; ++i) {
    int drow = i * 16 + (t >> 4);
    int sq = (t & 15) * 4;
    short4 y;
    y.x = f2bf(Tl[sq + 0][drow]);
    y.y = f2bf(Tl[sq + 1][drow]);
    y.z = f2bf(Tl[sq + 2][drow]);
    y.w = f2bf(Tl[sq + 3][drow]);
    *(short4*)&Vp[((size_t)bh * 128 + d0 + drow) * 1024 + s0 + sq] = y;
  }
}

// Main attention. K double-buffered in LDS (swizzled global_load_lds, counted
// vmcnt, raw s_barrier). V fragments direct from global (L2). Q RoPE'd in
// registers. Row-sum l via MFMA-with-ones. Defer-max (THR=8). 41 KB LDS ->
// 3 blocks/CU.
__global__ __launch_bounds__(256, 3) void attn_pre_k(
    const float* __restrict__ q, const short* __restrict__ Kp,
    const short* __restrict__ Vp, const float2* __restrict__ tab,
    float* __restrict__ out) {
  __shared__ char Kbuf[2][16384];        // K tile [64][128] bf16, swizzled
  __shared__ short Pb[4][16 * kVPad];    // per-wave P tile

  const int tid = threadIdx.x;
  const int w = tid >> 6;
  const int lane = tid & 63;
  const int lrow = lane & 15;
  const int hi = lane >> 4;
  const int lk8 = hi * 8;
  const int qt = kNT - 1 - (int)blockIdx.x;  // longest first
  const int hq = blockIdx.y;
  const int b = blockIdx.z;
  const int hkv = hq >> 2;
  const int q0 = qt * kQT;

  const char* Kh = (const char*)(Kp + ((size_t)b * 8 + hkv) * 1024 * 128);
  const short* Vh = Vp + ((size_t)b * 8 + hkv) * 128 * 1024;
  short* myP = &Pb[w][0];

#define STAGE_K(k0_, dstbuf_)                                                \
  do {                                                                       \
    char* Kd = &Kbuf[dstbuf_][0];                                            \
    _Pragma("unroll") for (int ii = 0; ii < 4; ++ii) {                       \
      int i = w * 4 + ii;                                                    \
      int row = i * 4 + hi;                                                  \
      int srcb = ((k0_) + row) * 256 + (((lane & 15) * 16) ^ ((row & 7) << 4)); \
      gload16(Kh + srcb, Kd + i * 1024);                                     \
    }                                                                        \
  } while (0)

  STAGE_K(0, 0);  // prologue: stage K tile 0

  // ---- Q fragments: RoPE applied fully in registers ----
  const int pos = q0 + w * 16 + lrow;
  const float* qrow = q + ((size_t)b * 1024 + pos) * 4096 + hq * kD;
  const float2* tp = tab + (size_t)pos * 64;
  bf16x8 qf[4];
#pragma unroll
  for (int pp = 0; pp < 2; ++pp) {
    int c = pp * 32 + lk8;
    float4 x1a = *(const float4*)&qrow[c];
    float4 x1b = *(const float4*)&qrow[c + 4];
    float4 x2a = *(const float4*)&qrow[c + 64];
    float4 x2b = *(const float4*)&qrow[c + 68];
    float4 ta = *(const float4*)&tp[c];
    float4 tb = *(const float4*)&tp[c + 2];
    float4 tc = *(const float4*)&tp[c + 4];
    float4 td = *(const float4*)&tp[c + 6];
    bf16x8 lo, hb;
    lo[0] = f2bf((x1a.x * ta.x - x2a.x * ta.y) * kScale);
    hb[0] = f2bf((x1a.x * ta.y + x2a.x * ta.x) * kScale);
    lo[1] = f2bf((x1a.y * ta.z - x2a.y * ta.w) * kScale);
    hb[1] = f2bf((x1a.y * ta.w + x2a.y * ta.z) * kScale);
    lo[2] = f2bf((x1a.z * tb.x - x2a.z * tb.y) * kScale);
    hb[2] = f2bf((x1a.z * tb.y + x2a.z * tb.x) * kScale);
    lo[3] = f2bf((x1a.w * tb.z - x2a.w * tb.w) * kScale);
    hb[3] = f2bf((x1a.w * tb.w + x2a.w * tb.z) * kScale);
    lo[4] = f2bf((x1b.x * tc.x - x2b.x * tc.y) * kScale);
    hb[4] = f2bf((x1b.x * tc.y + x2b.x * tc.x) * kScale);
    lo[5] = f2bf((x1b.y * tc.z - x2b.y * tc.w) * kScale);
    hb[5] = f2bf((x1b.y * tc.w + x2b.y * tc.z) * kScale);
    lo[6] = f2bf((x1b.z * td.x - x2b.z * td.y) * kScale);
    hb[6] = f2bf((x1b.z * td.y + x2b.z * td.x) * kScale);
    lo[7] = f2bf((x1b.w * td.z - x2b.w * td.w) * kScale);
    hb[7] = f2bf((x1b.w * td.w + x2b.w * td.z) * kScale);
    qf[pp] = lo;
    qf[pp + 2] = hb;
  }

  bf16x8 ones;
#pragma unroll
  for (int j = 0; j < 8; ++j) ones[j] = (short)0x3F80;

  float mS[4] = {-3e38f, -3e38f, -3e38f, -3e38f};
  f32x4 accl = {0.f, 0.f, 0.f, 0.f};
  f32x4 acc[8];
#pragma unroll
  for (int dt = 0; dt < 8; ++dt) acc[dt] = f32x4{0.f, 0.f, 0.f, 0.f};

  int buf = 0;
  for (int t = 0; t <= qt; ++t) {
    const int k0 = t * kKT;

    if (t < qt) {
      STAGE_K((t + 1) * kKT, buf ^ 1);
      VMCNT(4);  // tile-t stage (prev iter) done; tile-(t+1) stays in flight
    } else {
      VMCNT(0);
    }
    __builtin_amdgcn_sched_barrier(0);
    __builtin_amdgcn_s_barrier();
    __builtin_amdgcn_sched_barrier(0);

    const char* KsB = &Kbuf[buf][0];

    // ---- QK^T ----
    f32x4 sc[4];
    __builtin_amdgcn_s_setprio(1);
#pragma unroll
    for (int ct = 0; ct < 4; ++ct) {
      sc[ct] = f32x4{0.f, 0.f, 0.f, 0.f};
      int r = ct * 16 + lrow;
#pragma unroll
      for (int d = 0; d < 4; ++d) {
        bf16x8 kf = *(const bf16x8*)(KsB + r * 256 +
                                     ((d * 64 + hi * 16) ^ ((lrow & 7) << 4)));
        sc[ct] = __builtin_amdgcn_mfma_f32_16x16x32_bf16(qf[d], kf, sc[ct], 0, 0, 0);
      }
    }
    __builtin_amdgcn_s_setprio(0);
    __builtin_amdgcn_sched_barrier(0);
    __builtin_amdgcn_s_barrier();   // all waves done reading Kbuf[buf]
    __builtin_amdgcn_sched_barrier(0);

    // ---- V fragments direct from global (hidden under softmax) ----
    bf16x8 vf[16];
    {
      const short* Vb = Vh + (size_t)lrow * 1024 + k0 + lk8;
#pragma unroll
      for (int ks = 0; ks < 2; ++ks)
#pragma unroll
        for (int dt = 0; dt < 8; ++dt)
          vf[ks * 8 + dt] = *(const bf16x8*)(Vb + dt * 16 * 1024 + ks * 32);
    }

    // ---- causal mask on the diagonal tile ----
    if (t == qt) {
#pragma unroll
      for (int ct = 0; ct < 4; ++ct) {
        int col = ct * 16 + lrow;
#pragma unroll
        for (int r = 0; r < 4; ++r) {
          int row = w * 16 + hi * 4 + r;
          if (col > row) sc[ct][r] = -3e38f;
        }
      }
    }

    // ---- online softmax with defer-max (THR=8) ----
    float tm[4];
#pragma unroll
    for (int r = 0; r < 4; ++r) {
      float tv = fmaxf(fmaxf(sc[0][r], sc[1][r]), fmaxf(sc[2][r], sc[3][r]));
      tv = fmaxf(tv, __shfl_xor(tv, 1));
      tv = fmaxf(tv, __shfl_xor(tv, 2));
      tv = fmaxf(tv, __shfl_xor(tv, 4));
      tv = fmaxf(tv, __shfl_xor(tv, 8));
      tm[r] = tv;
    }
    int ok = (tm[0] <= mS[0] + 8.f) && (tm[1] <= mS[1] + 8.f) &&
             (tm[2] <= mS[2] + 8.f) && (tm[3] <= mS[3] + 8.f);
    if (!__all(ok)) {
#pragma unroll
      for (int r = 0; r < 4; ++r) {
        float mn = fmaxf(mS[r], tm[r]);
        float al = exp2f((mS[r] - mn) * kLog2e);
        mS[r] = mn;
        accl[r] *= al;
#pragma unroll
        for (int dt = 0; dt < 8; ++dt) acc[dt][r] *= al;
      }
    }
#pragma unroll
    for (int ct = 0; ct < 4; ++ct)
#pragma unroll
      for (int r = 0; r < 4; ++r) {
        float p = exp2f((sc[ct][r] - mS[r]) * kLog2e);
        myP[(hi * 4 + r) * kVPad + ct * 16 + lrow] = f2bf(p);
      }

    // ---- PV (+ row-sum via ones-MFMA) ----
    __builtin_amdgcn_s_setprio(1);
#pragma unroll
    for (int ks = 0; ks < 2; ++ks) {
      bf16x8 pf = *(const bf16x8*)&myP[lrow * kVPad + ks * 32 + lk8];
      accl = __builtin_amdgcn_mfma_f32_16x16x32_bf16(pf, ones, accl, 0, 0, 0);
#pragma unroll
      for (int dt = 0; dt < 8; ++dt)
        acc[dt] = __builtin_amdgcn_mfma_f32_16x16x32_bf16(pf, vf[ks * 8 + dt],
                                                          acc[dt], 0, 0, 0);
    }
    __builtin_amdgcn_s_setprio(0);
    buf ^= 1;
  }

  // ---- epilogue: out = acc / l ----
  float il[4];
#pragma unroll
  for (int r = 0; r < 4; ++r) il[r] = 1.f / accl[r];
  float* ob = out + ((size_t)b * kS + q0 + w * 16) * 4096 + hq * kD;
#pragma unroll
  for (int dt = 0; dt < 8; ++dt)
#pragma unroll
    for (int r = 0; r < 4; ++r)
      ob[(hi * 4 + r) * 4096 + dt * 16 + lrow] = acc[dt][r] * il[r];
#undef STAGE_K
}

// ---------------- fallback (small-ws path) ----------------
template <bool USE_TAB>
__global__ __launch_bounds__(256) void attn_k(
    const float* __restrict__ q, const float* __restrict__ k,
    const float* __restrict__ v, const float2* __restrict__ tab,
    float* __restrict__ out) {
  __shared__ short Ksf[kKT][kKPad];
  __shared__ short Vtf[kD][kVPad];
  __shared__ short Qbuf[kQT * kKPad];
  const int tid = threadIdx.x;
  const int w = tid >> 6;
  const int lane = tid & 63;
  const int lrow = lane & 15;
  const int lk8 = (lane >> 4) * 8;
  const int qt = (int)gridDim.x - 1 - (int)blockIdx.x;
  const int hq = blockIdx.y;
  const int b = blockIdx.z;
  const int hkv = hq >> 2;
  const int q0 = qt * kQT;
  const float* qb = q + (size_t)b * kS * 4096 + hq * kD;
  const float* kb = k + (size_t)b * kS * 1024 + hkv * kD;
  const float* vb = v + (size_t)b * kS * 1024 + hkv * kD;
#pragma unroll
  for (int it = 0; it < 16; ++it) {
    int pi = tid + it * 256;
    int row = pi >> 6, j = pi & 63;
    int pos = q0 + row;
    float x1 = qb[(size_t)pos * 4096 + j];
    float x2 = qb[(size_t)pos * 4096 + j + 64];
    float c, s;
    if (USE_TAB) { float2 t2 = tab[(pos << 6) + j]; c = t2.x; s = t2.y; }
    else { float ang = (float)pos * __expf(-(float)j * kFreqC); __sincosf(ang, &s, &c); }
    Qbuf[row * kKPad + j]      = f2bf((x1 * c - x2 * s) * kScale);
    Qbuf[row * kKPad + j + 64] = f2bf((x1 * s + x2 * c) * kScale);
  }
  __syncthreads();
  bf16x8 qf[4];
#pragma unroll
  for (int d = 0; d < 4; ++d)
    qf[d] = *(const bf16x8*)&Qbuf[(w * 16 + lrow) * kKPad + d * 32 + lk8];
  __syncthreads();
  short* myP = Qbuf + w * 16 * kVPad;
  float mS[4] = {-3e38f, -3e38f, -3e38f, -3e38f};
  float lS[4] = {0.f, 0.f, 0.f, 0.f};
  f32x4 acc[8];
#pragma unroll
  for (int dt = 0; dt < 8; ++dt) acc[dt] = f32x4{0.f, 0.f, 0.f, 0.f};
  for (int kt = 0; kt <= qt; ++kt) {
    const int k0 = kt * kKT;
#pragma unroll
    for (int it = 0; it < 16; ++it) {
      int pi = tid + it * 256;
      int row = pi >> 6, j = pi & 63;
      int pos = k0 + row;
      float x1 = kb[(size_t)pos * 1024 + j];
      float x2 = kb[(size_t)pos * 1024 + j + 64];
      float c, s;
      if (USE_TAB) { float2 t2 = tab[(pos << 6) + j]; c = t2.x; s = t2.y; }
      else { float ang = (float)pos * __expf(-(float)j * kFreqC); __sincosf(ang, &s, &c); }
      Ksf[row][j]      = f2bf(x1 * c - x2 * s);
      Ksf[row][j + 64] = f2bf(x1 * s + x2 * c);
    }
#pragma unroll
    for (int it = 0; it < 8; ++it) {
      int f = (tid + it * 256) * 4;
      int row = f >> 7, col = f & 127;
      const float4 v4 = *(const float4*)(vb + (size_t)(k0 + row) * 1024 + col);
      Vtf[col + 0][row] = f2bf(v4.x);
      Vtf[col + 1][row] = f2bf(v4.y);
      Vtf[col + 2][row] = f2bf(v4.z);
      Vtf[col + 3][row] = f2bf(v4.w);
    }
    __syncthreads();
    f32x4 sc[4];
#pragma unroll
    for (int ct = 0; ct < 4; ++ct) {
      sc[ct] = f32x4{0.f, 0.f, 0.f, 0.f};
#pragma unroll
      for (int d = 0; d < 4; ++d) {
        bf16x8 kf = *(const bf16x8*)&Ksf[ct * 16 + lrow][d * 32 + lk8];
        sc[ct] = __builtin_amdgcn_mfma_f32_16x16x32_bf16(qf[d], kf, sc[ct], 0, 0, 0);
      }
    }
    if (kt == qt) {
#pragma unroll
      for (int ct = 0; ct < 4; ++ct) {
        int col = ct * 16 + lrow;
#pragma unroll
        for (int r = 0; r < 4; ++r) {
          int row = w * 16 + (lane >> 4) * 4 + r;
          if (col > row) sc[ct][r] = -3e38f;
        }
      }
    }
#pragma unroll
    for (int r = 0; r < 4; ++r) {
      float t = fmaxf(fmaxf(sc[0][r], sc[1][r]), fmaxf(sc[2][r], sc[3][r]));
      t = fmaxf(t, __shfl_xor(t, 1));
      t = fmaxf(t, __shfl_xor(t, 2));
      t = fmaxf(t, __shfl_xor(t, 4));
      t = fmaxf(t, __shfl_xor(t, 8));
      float mn = fmaxf(mS[r], t);
      float al = exp2f((mS[r] - mn) * kLog2e);
      float rs = 0.f;
#pragma unroll
      for (int ct = 0; ct < 4; ++ct) {
        float p = exp2f((sc[ct][r] - mn) * kLog2e);
        sc[ct][r] = p;
        rs += p;
      }
      rs += __shfl_xor(rs, 1);
      rs += __shfl_xor(rs, 2);
      rs += __shfl_xor(rs, 4);
      rs += __shfl_xor(rs, 8);
      lS[r] = lS[r] * al + rs;
      mS[r] = mn;
#pragma unroll
      for (int dt = 0; dt < 8; ++dt) acc[dt][r] *= al;
    }
#pragma unroll
    for (int ct = 0; ct < 4; ++ct)
#pragma unroll
      for (int r = 0; r < 4; ++r)
        myP[((lane >> 4) * 4 + r) * kVPad + ct * 16 + lrow] = f2bf(sc[ct][r]);
#pragma unroll
    for (int ks = 0; ks < 2; ++ks) {
      bf16x8 pf = *(const bf16x8*)&myP[lrow * kVPad + ks * 32 + lk8];
#pragma unroll
      for (int dt = 0; dt < 8; ++dt) {
        bf16x8 vf = *(const bf16x8*)&Vtf[dt * 16 + lrow][ks * 32 + lk8];
        acc[dt] = __builtin_amdgcn_mfma_f32_16x16x32_bf16(pf, vf, acc[dt], 0, 0, 0);
      }
    }
    __syncthreads();
  }
  float il[4];
#pragma unroll
  for (int r = 0; r < 4; ++r) il[r] = 1.f / lS[r];
  float* ob = out + ((size_t)b * kS + q0 + w * 16) * 4096 + hq * kD;
#pragma unroll
  for (int dt = 0; dt < 8; ++dt)
#pragma unroll
    for (int r = 0; r < 4; ++r)
      ob[((lane >> 4) * 4 + r) * 4096 + dt * 16 + lrow] = acc[dt][r] * il[r];
}

extern "C" void kernel_launch(void* const* d_in, const int* in_sizes, int n_in,
                              void* d_out, int out_size, void* d_ws, size_t ws_size,
                              hipStream_t stream) {
  const float* q = (const float*)d_in[0];
  const float* k = (const float*)d_in[1];
  const float* v = (const float*)d_in[2];
  float* out = (float*)d_out;

  if (ws_size >= kWsNeed) {
    float2* tab = (float2*)((char*)d_ws + kTabOff);
    short* Kp = (short*)((char*)d_ws + kKOff);
    short* Vp = (short*)((char*)d_ws + kVOff);
    rope_table_k<<<256, 256, 0, stream>>>(tab);
    rope_k_only<<<1024, 256, 0, stream>>>(k, tab, Kp);
    v_tr_k<<<512, 256, 0, stream>>>(v, Vp);
    dim3 grid(kNT, 32, kB);  // (16, 32, 2)
    attn_pre_k<<<grid, 256, 0, stream>>>(q, Kp, Vp, tab, out);
  } else if (ws_size >= 512 * 1024) {
    float2* tab = (float2*)d_ws;
    rope_table_k<<<256, 256, 0, stream>>>(tab);
    dim3 grid(kNT, 32, kB);
    attn_k<true><<<grid, 256, 0, stream>>>(q, k, v, tab, out);
  } else {
    dim3 grid(kNT, 32, kB);
    attn_k<false><<<grid, 256, 0, stream>>>(q, k, v, nullptr, out);
  }
}

// Round 6
// 71.726 us; speedup vs baseline: 2.4415x; 2.4415x over previous
//
#include <hip/hip_runtime.h>
#include <math.h>

typedef __attribute__((ext_vector_type(4))) float f32x4;
typedef __attribute__((ext_vector_type(8))) short bf16x8;

namespace {
constexpr int kB = 2;
constexpr int kS = 1024;
constexpr int kD = 128;
constexpr int kQT = 64;   // q rows per block-tile (16 per wave)
constexpr int kKT = 64;   // kv rows per tile
constexpr int kNT = kS / kQT;  // 16 q-tiles; block pairs (p, 15-p)
constexpr float kScale = 0.08838834764831845f;   // 1/sqrt(128)
constexpr float kLog2e = 1.4426950408889634f;
constexpr float kFreqC = 0.20503692777194262f;   // ln(500000)/64
constexpr int kKPad = 136;  // fallback kernel pads
constexpr int kVPad = 72;

// workspace layout (bytes)
constexpr size_t kTabOff = 0;                       // float2[1024*64] = 512 KB
constexpr size_t kQOff = 512 * 1024;                // bf16 [2][1024][32][128]
constexpr size_t kKOff = kQOff + 16777216;          // bf16 [2][8][1024][128]
constexpr size_t kVOff = kKOff + 4194304;           // bf16 [2][8][128][1024]
constexpr size_t kWsNeed = kVOff + 4194304;         // 25,690,112 B
}

#define VMCNT(n) asm volatile("s_waitcnt vmcnt(" #n ")" ::: "memory")

__device__ inline short f2bf(float f) {  // RNE float->bf16
  union { float f; unsigned u; } c{f};
  unsigned r = c.u + 0x7fffu + ((c.u >> 16) & 1u);
  return (short)(r >> 16);
}

__device__ inline void gload16(const void* g, void* l) {
  __builtin_amdgcn_global_load_lds(
      (const __attribute__((address_space(1))) void*)g,
      (__attribute__((address_space(3))) void*)l, 16, 0, 0);
}

// tab[pos*64 + j] = (cos(pos*f_j), sin(pos*f_j))
__global__ __launch_bounds__(256) void rope_table_k(float2* __restrict__ tab) {
  int t = blockIdx.x * 256 + threadIdx.x;  // 1024*64
  int pos = t >> 6, j = t & 63;
  float ang = (float)pos * expf(-(float)j * kFreqC);
  float sn, cs;
  sincosf(ang, &sn, &cs);
  tab[t] = make_float2(cs, sn);
}

// Fused prepass: blocks [0,5120) RoPE Q (scaled) + K -> bf16;
// blocks [5120,5632) transpose V -> [b][hkv][d][s] bf16.
__global__ __launch_bounds__(256) void prep_k(
    const float* __restrict__ q, const float* __restrict__ k,
    const float* __restrict__ v, const float2* __restrict__ tab,
    short* __restrict__ Qp, short* __restrict__ Kp, short* __restrict__ Vp) {
  __shared__ float Tl[64][68];
  int bid = blockIdx.x;
  if (bid < 5120) {
    int gt = bid * 256 + threadIdx.x;
    const float* src;
    short* dst;
    size_t sidx, didx;
    int s, j;
    float sc;
    if (gt < 1048576) {  // Q part: [b][s][h=32][j4=16]
      j = (gt & 15) * 4;
      int h = (gt >> 4) & 31;
      s = (gt >> 9) & 1023;
      int b = gt >> 19;
      sidx = ((size_t)b * 1024 + s) * 4096 + h * 128 + j;
      didx = (((size_t)b * 1024 + s) * 32 + h) * 128 + j;
      src = q; dst = Qp; sc = kScale;
    } else {             // K part: [b][s][h=8][j4=16]
      int t2 = gt - 1048576;
      j = (t2 & 15) * 4;
      int h = (t2 >> 4) & 7;
      s = (t2 >> 7) & 1023;
      int b = t2 >> 17;
      sidx = ((size_t)b * 1024 + s) * 1024 + h * 128 + j;
      didx = (((size_t)b * 8 + h) * 1024 + s) * 128 + j;
      src = k; dst = Kp; sc = 1.0f;
    }
    float4 x1 = *(const float4*)&src[sidx];
    float4 x2 = *(const float4*)&src[sidx + 64];
    float4 t0 = *(const float4*)&tab[s * 64 + j];      // c0 s0 c1 s1
    float4 t1 = *(const float4*)&tab[s * 64 + j + 2];  // c2 s2 c3 s3
    short4 y1, y2;
    y1.x = f2bf((x1.x * t0.x - x2.x * t0.y) * sc);
    y2.x = f2bf((x1.x * t0.y + x2.x * t0.x) * sc);
    y1.y = f2bf((x1.y * t0.z - x2.y * t0.w) * sc);
    y2.y = f2bf((x1.y * t0.w + x2.y * t0.z) * sc);
    y1.z = f2bf((x1.z * t1.x - x2.z * t1.y) * sc);
    y2.z = f2bf((x1.z * t1.y + x2.z * t1.x) * sc);
    y1.w = f2bf((x1.w * t1.z - x2.w * t1.w) * sc);
    y2.w = f2bf((x1.w * t1.w + x2.w * t1.z) * sc);
    *(short4*)&dst[didx] = y1;
    *(short4*)&dst[didx + 64] = y2;
  } else {
    int blk = bid - 5120;
    int bh = blk >> 5;            // 0..15 = b*8+h
    int rem = blk & 31;
    int s0 = (rem >> 1) * 64;
    int d0 = (rem & 1) * 64;
    int t = threadIdx.x;
#pragma unroll
    for (int i = 0; i < 4; ++i) {
      int srow = i * 16 + (t >> 4);
      int scol = (t & 15) * 4;
      float4 x = *(const float4*)&v[((size_t)(bh >> 3) * 1024 + s0 + srow) * 1024 +
                                    (bh & 7) * 128 + d0 + scol];
      *(float4*)&Tl[srow][scol] = x;
    }
    __syncthreads();
#pragma unroll
    for (int i = 0; i < 4; ++i) {
      int drow = i * 16 + (t >> 4);
      int sq = (t & 15) * 4;
      short4 y;
      y.x = f2bf(Tl[sq + 0][drow]);
      y.y = f2bf(Tl[sq + 1][drow]);
      y.z = f2bf(Tl[sq + 2][drow]);
      y.w = f2bf(Tl[sq + 3][drow]);
      *(short4*)&Vp[((size_t)bh * 128 + d0 + drow) * 1024 + s0 + sq] = y;
    }
  }
}

// Main attention: pre-RoPE'd bf16, triangle-paired q-tiles (uniform 17 iters),
// double-buffered K/V staged via global_load_lds with counted vmcnt + raw
// s_barrier 2-phase pipeline. XOR-swizzled LDS. Row-sum l via ones-MFMA;
// defer-max THR=8; setprio around MFMA clusters.
__global__ __launch_bounds__(256) void attn_pre_k(
    const short* __restrict__ Qp, const short* __restrict__ Kp,
    const short* __restrict__ Vp, float* __restrict__ out) {
  __shared__ char KV[2][32768];          // per buf: K [64][128] | Vt [128][64]
  __shared__ short Pb[4][16 * kVPad];    // per-wave P tile

  const int tid = threadIdx.x;
  const int w = tid >> 6;
  const int lane = tid & 63;
  const int lrow = lane & 15;
  const int hi = lane >> 4;
  const int lk8 = hi * 8;
  const int pair = blockIdx.x;           // 0..7
  const int hq = blockIdx.y;
  const int b = blockIdx.z;
  const int hkv = hq >> 2;

  const char* Kh = (const char*)(Kp + ((size_t)b * 8 + hkv) * 1024 * 128);
  const char* Vh = (const char*)(Vp + ((size_t)b * 8 + hkv) * 128 * 1024);
  short* myP = &Pb[w][0];

  bf16x8 ones;
#pragma unroll
  for (int j = 0; j < 8; ++j) ones[j] = (short)0x3F80;

  // stage one 64-row K tile + 64-col Vt tile (8 gload16 per thread)
#define STAGE_TILE(k0_, dstbuf_)                                            \
  {                                                                         \
    char* Kd = KV[dstbuf_];                                                 \
    char* Vd = KV[dstbuf_] + 16384;                                         \
    _Pragma("unroll") for (int ii = 0; ii < 4; ++ii) {                      \
      int i = w * 4 + ii;                                                   \
      int row = i * 4 + (lane >> 4);                                        \
      int srcb = ((k0_) + row) * 256 + (((lane & 15) * 16) ^ ((row & 7) << 4)); \
      gload16(Kh + srcb, Kd + i * 1024);                                    \
    }                                                                       \
    _Pragma("unroll") for (int ii = 0; ii < 4; ++ii) {                      \
      int i = w * 4 + ii;                                                   \
      int row = i * 8 + (lane >> 3);                                        \
      int srcb = row * 2048 + (k0_)*2 + (((lane & 7) * 16) ^ ((row & 7) << 4)); \
      gload16(Vh + srcb, Vd + i * 1024);                                    \
    }                                                                       \
  }

#pragma unroll
  for (int half = 0; half < 2; ++half) {
    const int qt = half ? (kNT - 1 - pair) : pair;
    const int q0 = qt * kQT;

    // Q fragments straight from global bf16
    const short* Qrow =
        Qp + (((size_t)b * 1024 + q0 + w * 16 + lrow) * 32 + hq) * 128;
    bf16x8 qf[4];
#pragma unroll
    for (int d = 0; d < 4; ++d) qf[d] = *(const bf16x8*)&Qrow[d * 32 + lk8];

    float mS[4] = {-3e38f, -3e38f, -3e38f, -3e38f};
    f32x4 accl = {0.f, 0.f, 0.f, 0.f};
    f32x4 acc[8];
#pragma unroll
    for (int dt = 0; dt < 8; ++dt) acc[dt] = f32x4{0.f, 0.f, 0.f, 0.f};

    STAGE_TILE(0, 0);  // prologue
    int buf = 0;

    for (int t = 0; t <= qt; ++t) {
      if (t < qt) {
        STAGE_TILE((t + 1) * kKT, buf ^ 1);
        VMCNT(8);   // tile-t loads done; tile-(t+1)'s 8 stay in flight
      } else {
        VMCNT(0);
      }
      __builtin_amdgcn_sched_barrier(0);
      __builtin_amdgcn_s_barrier();
      __builtin_amdgcn_sched_barrier(0);

      const char* KsB = KV[buf];
      const char* VtB = KV[buf] + 16384;

      // ---- QK^T ----
      f32x4 sc[4];
      __builtin_amdgcn_s_setprio(1);
#pragma unroll
      for (int ct = 0; ct < 4; ++ct) {
        sc[ct] = f32x4{0.f, 0.f, 0.f, 0.f};
        int r = ct * 16 + lrow;
#pragma unroll
        for (int d = 0; d < 4; ++d) {
          bf16x8 kf = *(const bf16x8*)(KsB + r * 256 +
                                       ((d * 64 + hi * 16) ^ ((lrow & 7) << 4)));
          sc[ct] = __builtin_amdgcn_mfma_f32_16x16x32_bf16(qf[d], kf, sc[ct], 0, 0, 0);
        }
      }
      __builtin_amdgcn_s_setprio(0);

      // ---- causal mask on the diagonal tile ----
      if (t == qt) {
#pragma unroll
        for (int ct = 0; ct < 4; ++ct) {
          int col = ct * 16 + lrow;
#pragma unroll
          for (int r = 0; r < 4; ++r) {
            int row = w * 16 + hi * 4 + r;
            if (col > row) sc[ct][r] = -3e38f;
          }
        }
      }

      // ---- online softmax: defer-max (THR=8); l via ones-MFMA below ----
      float tm[4];
#pragma unroll
      for (int r = 0; r < 4; ++r) {
        float tv = fmaxf(fmaxf(sc[0][r], sc[1][r]), fmaxf(sc[2][r], sc[3][r]));
        tv = fmaxf(tv, __shfl_xor(tv, 1));
        tv = fmaxf(tv, __shfl_xor(tv, 2));
        tv = fmaxf(tv, __shfl_xor(tv, 4));
        tv = fmaxf(tv, __shfl_xor(tv, 8));
        tm[r] = tv;
      }
      int ok = (tm[0] <= mS[0] + 8.f) && (tm[1] <= mS[1] + 8.f) &&
               (tm[2] <= mS[2] + 8.f) && (tm[3] <= mS[3] + 8.f);
      if (!__all(ok)) {
#pragma unroll
        for (int r = 0; r < 4; ++r) {
          float mn = fmaxf(mS[r], tm[r]);
          float al = exp2f((mS[r] - mn) * kLog2e);
          mS[r] = mn;
          accl[r] *= al;
#pragma unroll
          for (int dt = 0; dt < 8; ++dt) acc[dt][r] *= al;
        }
      }

      // ---- P -> per-wave LDS (exp fused into the write) ----
#pragma unroll
      for (int ct = 0; ct < 4; ++ct)
#pragma unroll
        for (int r = 0; r < 4; ++r) {
          float p = exp2f((sc[ct][r] - mS[r]) * kLog2e);
          myP[(hi * 4 + r) * kVPad + ct * 16 + lrow] = f2bf(p);
        }

      // ---- PV (+ row-sum l via ones-MFMA) ----
      __builtin_amdgcn_s_setprio(1);
#pragma unroll
      for (int ks = 0; ks < 2; ++ks) {
        bf16x8 pf = *(const bf16x8*)&myP[lrow * kVPad + ks * 32 + lk8];
        accl = __builtin_amdgcn_mfma_f32_16x16x32_bf16(pf, ones, accl, 0, 0, 0);
#pragma unroll
        for (int dt = 0; dt < 8; ++dt) {
          int rv = dt * 16 + lrow;
          bf16x8 vf = *(const bf16x8*)(VtB + rv * 128 +
                                       ((ks * 64 + hi * 16) ^ ((lrow & 7) << 4)));
          acc[dt] = __builtin_amdgcn_mfma_f32_16x16x32_bf16(pf, vf, acc[dt], 0, 0, 0);
        }
      }
      __builtin_amdgcn_s_setprio(0);
      __builtin_amdgcn_sched_barrier(0);
      __builtin_amdgcn_s_barrier();   // all reads of KV[buf] done before overwrite
      __builtin_amdgcn_sched_barrier(0);
      buf ^= 1;
    }

    // ---- epilogue: out = acc / l ----
    float il[4];
#pragma unroll
    for (int r = 0; r < 4; ++r) il[r] = 1.f / accl[r];
    float* ob = out + ((size_t)b * kS + q0 + w * 16) * 4096 + hq * kD;
#pragma unroll
    for (int dt = 0; dt < 8; ++dt)
#pragma unroll
      for (int r = 0; r < 4; ++r)
        ob[(hi * 4 + r) * 4096 + dt * 16 + lrow] = acc[dt][r] * il[r];
  }
#undef STAGE_TILE
}

// ---------------- fallback (small-ws path) ----------------
template <bool USE_TAB>
__global__ __launch_bounds__(256) void attn_k(
    const float* __restrict__ q, const float* __restrict__ k,
    const float* __restrict__ v, const float2* __restrict__ tab,
    float* __restrict__ out) {
  __shared__ short Ksf[kKT][kKPad];
  __shared__ short Vtf[kD][kVPad];
  __shared__ short Qbuf[kQT * kKPad];
  const int tid = threadIdx.x;
  const int w = tid >> 6;
  const int lane = tid & 63;
  const int lrow = lane & 15;
  const int lk8 = (lane >> 4) * 8;
  const int qt = (int)gridDim.x - 1 - (int)blockIdx.x;
  const int hq = blockIdx.y;
  const int b = blockIdx.z;
  const int hkv = hq >> 2;
  const int q0 = qt * kQT;
  const float* qb = q + (size_t)b * kS * 4096 + hq * kD;
  const float* kb = k + (size_t)b * kS * 1024 + hkv * kD;
  const float* vb = v + (size_t)b * kS * 1024 + hkv * kD;
#pragma unroll
  for (int it = 0; it < 16; ++it) {
    int pi = tid + it * 256;
    int row = pi >> 6, j = pi & 63;
    int pos = q0 + row;
    float x1 = qb[(size_t)pos * 4096 + j];
    float x2 = qb[(size_t)pos * 4096 + j + 64];
    float c, s;
    if (USE_TAB) { float2 t2 = tab[(pos << 6) + j]; c = t2.x; s = t2.y; }
    else { float ang = (float)pos * __expf(-(float)j * kFreqC); __sincosf(ang, &s, &c); }
    Qbuf[row * kKPad + j]      = f2bf((x1 * c - x2 * s) * kScale);
    Qbuf[row * kKPad + j + 64] = f2bf((x1 * s + x2 * c) * kScale);
  }
  __syncthreads();
  bf16x8 qf[4];
#pragma unroll
  for (int d = 0; d < 4; ++d)
    qf[d] = *(const bf16x8*)&Qbuf[(w * 16 + lrow) * kKPad + d * 32 + lk8];
  __syncthreads();
  short* myP = Qbuf + w * 16 * kVPad;
  float mS[4] = {-3e38f, -3e38f, -3e38f, -3e38f};
  float lS[4] = {0.f, 0.f, 0.f, 0.f};
  f32x4 acc[8];
#pragma unroll
  for (int dt = 0; dt < 8; ++dt) acc[dt] = f32x4{0.f, 0.f, 0.f, 0.f};
  for (int kt = 0; kt <= qt; ++kt) {
    const int k0 = kt * kKT;
#pragma unroll
    for (int it = 0; it < 16; ++it) {
      int pi = tid + it * 256;
      int row = pi >> 6, j = pi & 63;
      int pos = k0 + row;
      float x1 = kb[(size_t)pos * 1024 + j];
      float x2 = kb[(size_t)pos * 1024 + j + 64];
      float c, s;
      if (USE_TAB) { float2 t2 = tab[(pos << 6) + j]; c = t2.x; s = t2.y; }
      else { float ang = (float)pos * __expf(-(float)j * kFreqC); __sincosf(ang, &s, &c); }
      Ksf[row][j]      = f2bf(x1 * c - x2 * s);
      Ksf[row][j + 64] = f2bf(x1 * s + x2 * c);
    }
#pragma unroll
    for (int it = 0; it < 8; ++it) {
      int f = (tid + it * 256) * 4;
      int row = f >> 7, col = f & 127;
      const float4 v4 = *(const float4*)(vb + (size_t)(k0 + row) * 1024 + col);
      Vtf[col + 0][row] = f2bf(v4.x);
      Vtf[col + 1][row] = f2bf(v4.y);
      Vtf[col + 2][row] = f2bf(v4.z);
      Vtf[col + 3][row] = f2bf(v4.w);
    }
    __syncthreads();
    f32x4 sc[4];
#pragma unroll
    for (int ct = 0; ct < 4; ++ct) {
      sc[ct] = f32x4{0.f, 0.f, 0.f, 0.f};
#pragma unroll
      for (int d = 0; d < 4; ++d) {
        bf16x8 kf = *(const bf16x8*)&Ksf[ct * 16 + lrow][d * 32 + lk8];
        sc[ct] = __builtin_amdgcn_mfma_f32_16x16x32_bf16(qf[d], kf, sc[ct], 0, 0, 0);
      }
    }
    if (kt == qt) {
#pragma unroll
      for (int ct = 0; ct < 4; ++ct) {
        int col = ct * 16 + lrow;
#pragma unroll
        for (int r = 0; r < 4; ++r) {
          int row = w * 16 + (lane >> 4) * 4 + r;
          if (col > row) sc[ct][r] = -3e38f;
        }
      }
    }
#pragma unroll
    for (int r = 0; r < 4; ++r) {
      float t = fmaxf(fmaxf(sc[0][r], sc[1][r]), fmaxf(sc[2][r], sc[3][r]));
      t = fmaxf(t, __shfl_xor(t, 1));
      t = fmaxf(t, __shfl_xor(t, 2));
      t = fmaxf(t, __shfl_xor(t, 4));
      t = fmaxf(t, __shfl_xor(t, 8));
      float mn = fmaxf(mS[r], t);
      float al = exp2f((mS[r] - mn) * kLog2e);
      float rs = 0.f;
#pragma unroll
      for (int ct = 0; ct < 4; ++ct) {
        float p = exp2f((sc[ct][r] - mn) * kLog2e);
        sc[ct][r] = p;
        rs += p;
      }
      rs += __shfl_xor(rs, 1);
      rs += __shfl_xor(rs, 2);
      rs += __shfl_xor(rs, 4);
      rs += __shfl_xor(rs, 8);
      lS[r] = lS[r] * al + rs;
      mS[r] = mn;
#pragma unroll
      for (int dt = 0; dt < 8; ++dt) acc[dt][r] *= al;
    }
#pragma unroll
    for (int ct = 0; ct < 4; ++ct)
#pragma unroll
      for (int r = 0; r < 4; ++r)
        myP[((lane >> 4) * 4 + r) * kVPad + ct * 16 + lrow] = f2bf(sc[ct][r]);
#pragma unroll
    for (int ks = 0; ks < 2; ++ks) {
      bf16x8 pf = *(const bf16x8*)&myP[lrow * kVPad + ks * 32 + lk8];
#pragma unroll
      for (int dt = 0; dt < 8; ++dt) {
        bf16x8 vf = *(const bf16x8*)&Vtf[dt * 16 + lrow][ks * 32 + lk8];
        acc[dt] = __builtin_amdgcn_mfma_f32_16x16x32_bf16(pf, vf, acc[dt], 0, 0, 0);
      }
    }
    __syncthreads();
  }
  float il[4];
#pragma unroll
  for (int r = 0; r < 4; ++r) il[r] = 1.f / lS[r];
  float* ob = out + ((size_t)b * kS + q0 + w * 16) * 4096 + hq * kD;
#pragma unroll
  for (int dt = 0; dt < 8; ++dt)
#pragma unroll
    for (int r = 0; r < 4; ++r)
      ob[((lane >> 4) * 4 + r) * 4096 + dt * 16 + lrow] = acc[dt][r] * il[r];
}

extern "C" void kernel_launch(void* const* d_in, const int* in_sizes, int n_in,
                              void* d_out, int out_size, void* d_ws, size_t ws_size,
                              hipStream_t stream) {
  const float* q = (const float*)d_in[0];
  const float* k = (const float*)d_in[1];
  const float* v = (const float*)d_in[2];
  float* out = (float*)d_out;

  if (ws_size >= kWsNeed) {
    float2* tab = (float2*)((char*)d_ws + kTabOff);
    short* Qp = (short*)((char*)d_ws + kQOff);
    short* Kp = (short*)((char*)d_ws + kKOff);
    short* Vp = (short*)((char*)d_ws + kVOff);
    rope_table_k<<<256, 256, 0, stream>>>(tab);
    prep_k<<<5632, 256, 0, stream>>>(q, k, v, tab, Qp, Kp, Vp);
    dim3 grid(kNT / 2, 32, kB);  // (8, 32, 2) — paired q-tiles
    attn_pre_k<<<grid, 256, 0, stream>>>(Qp, Kp, Vp, out);
  } else if (ws_size >= 512 * 1024) {
    float2* tab = (float2*)d_ws;
    rope_table_k<<<256, 256, 0, stream>>>(tab);
    dim3 grid(kNT, 32, kB);
    attn_k<true><<<grid, 256, 0, stream>>>(q, k, v, tab, out);
  } else {
    dim3 grid(kNT, 32, kB);
    attn_k<false><<<grid, 256, 0, stream>>>(q, k, v, nullptr, out);
  }
}

// Round 7
// 70.674 us; speedup vs baseline: 2.4778x; 1.0149x over previous
//
#include <hip/hip_runtime.h>
#include <math.h>

typedef __attribute__((ext_vector_type(4))) float f32x4;
typedef __attribute__((ext_vector_type(8))) short bf16x8;

namespace {
constexpr int kB = 2;
constexpr int kS = 1024;
constexpr int kD = 128;
constexpr int kQT = 64;   // q rows per block (16 per wave)
constexpr int kKT = 32;   // kv rows per tile (swapped kernel)
constexpr int kNT = kS / kQT;  // 16 q-tiles
constexpr float kScale = 0.08838834764831845f;   // 1/sqrt(128)
constexpr float kLog2e = 1.4426950408889634f;
constexpr float kFreqC = 0.20503692777194262f;   // ln(500000)/64
constexpr int kKPad = 136;  // fallback kernel pads
constexpr int kVPad = 72;

// workspace layout (bytes)
constexpr size_t kTabOff = 0;                       // float2[1024*64] = 512 KB
constexpr size_t kKOff = 512 * 1024;                // bf16 [2][8][1024][128]
constexpr size_t kVOff = kKOff + 4194304;           // bf16 [2][8][128][1024]
constexpr size_t kWsNeed = kVOff + 4194304;         // ~8.9 MB
}

#define VMCNT(n) asm volatile("s_waitcnt vmcnt(" #n ")" ::: "memory")

__device__ inline short f2bf(float f) {  // RNE float->bf16
  union { float f; unsigned u; } c{f};
  unsigned r = c.u + 0x7fffu + ((c.u >> 16) & 1u);
  return (short)(r >> 16);
}

__device__ inline unsigned pkbf(float a, float b) {  // (bf16(b)<<16)|bf16(a)
  unsigned r;
  asm("v_cvt_pk_bf16_f32 %0, %1, %2" : "=v"(r) : "v"(a), "v"(b));
  return r;
}

__device__ inline void gload16(const void* g, void* l) {
  __builtin_amdgcn_global_load_lds(
      (const __attribute__((address_space(1))) void*)g,
      (__attribute__((address_space(3))) void*)l, 16, 0, 0);
}

// tab[pos*64 + j] = (cos(pos*f_j), sin(pos*f_j))
__global__ __launch_bounds__(256) void rope_table_k(float2* __restrict__ tab) {
  int t = blockIdx.x * 256 + threadIdx.x;  // 1024*64
  int pos = t >> 6, j = t & 63;
  float ang = (float)pos * expf(-(float)j * kFreqC);
  float sn, cs;
  sincosf(ang, &sn, &cs);
  tab[t] = make_float2(cs, sn);
}

// Fused prepass: blocks [0,1024) RoPE K -> bf16 [b][h][s][d];
// blocks [1024,1536) transpose V -> [b][hkv][d][s] bf16.
__global__ __launch_bounds__(256) void prep_k(
    const float* __restrict__ k, const float* __restrict__ v,
    const float2* __restrict__ tab, short* __restrict__ Kp,
    short* __restrict__ Vp) {
  __shared__ float Tl[64][68];
  int bid = blockIdx.x;
  if (bid < 1024) {
    int t2 = bid * 256 + threadIdx.x;  // 262144
    int j = (t2 & 15) * 4;
    int h = (t2 >> 4) & 7;
    int s = (t2 >> 7) & 1023;
    int b = t2 >> 17;
    size_t sidx = ((size_t)b * 1024 + s) * 1024 + h * 128 + j;
    size_t didx = (((size_t)b * 8 + h) * 1024 + s) * 128 + j;
    float4 x1 = *(const float4*)&k[sidx];
    float4 x2 = *(const float4*)&k[sidx + 64];
    float4 t0 = *(const float4*)&tab[s * 64 + j];      // c0 s0 c1 s1
    float4 t1 = *(const float4*)&tab[s * 64 + j + 2];  // c2 s2 c3 s3
    short4 y1, y2;
    y1.x = f2bf(x1.x * t0.x - x2.x * t0.y);
    y2.x = f2bf(x1.x * t0.y + x2.x * t0.x);
    y1.y = f2bf(x1.y * t0.z - x2.y * t0.w);
    y2.y = f2bf(x1.y * t0.w + x2.y * t0.z);
    y1.z = f2bf(x1.z * t1.x - x2.z * t1.y);
    y2.z = f2bf(x1.z * t1.y + x2.z * t1.x);
    y1.w = f2bf(x1.w * t1.z - x2.w * t1.w);
    y2.w = f2bf(x1.w * t1.w + x2.w * t1.z);
    *(short4*)&Kp[didx] = y1;
    *(short4*)&Kp[didx + 64] = y2;
  } else {
    int blk = bid - 1024;
    int bh = blk >> 5;            // 0..15 = b*8+h
    int rem = blk & 31;
    int s0 = (rem >> 1) * 64;
    int d0 = (rem & 1) * 64;
    int t = threadIdx.x;
#pragma unroll
    for (int i = 0; i < 4; ++i) {
      int srow = i * 16 + (t >> 4);
      int scol = (t & 15) * 4;
      float4 x = *(const float4*)&v[((size_t)(bh >> 3) * 1024 + s0 + srow) * 1024 +
                                    (bh & 7) * 128 + d0 + scol];
      *(float4*)&Tl[srow][scol] = x;
    }
    __syncthreads();
#pragma unroll
    for (int i = 0; i < 4; ++i) {
      int drow = i * 16 + (t >> 4);
      int sq = (t & 15) * 4;
      short4 y;
      y.x = f2bf(Tl[sq + 0][drow]);
      y.y = f2bf(Tl[sq + 1][drow]);
      y.z = f2bf(Tl[sq + 2][drow]);
      y.w = f2bf(Tl[sq + 3][drow]);
      *(short4*)&Vp[((size_t)bh * 128 + d0 + drow) * 1024 + s0 + sq] = y;
    }
  }
}

// Main attention (swapped QK^T, in-register softmax, no P-LDS).
// KT=32 K/V double-buffer (32 KB LDS -> 4 blocks/CU, grid 1024 all-resident).
// Swapped mfma(K,Q): lane holds P[q=lane&15][key=ct*16+hi*4+r].
// P->A-frag redistribution: 4 cvt_pk + 8 shfl + selects, in registers.
__global__ __launch_bounds__(256, 4) void attn_swp_k(
    const float* __restrict__ q, const short* __restrict__ Kp,
    const short* __restrict__ Vp, const float2* __restrict__ tab,
    float* __restrict__ out) {
  __shared__ char KV[2][16384];  // per buf: K [32][128]bf16 | Vt [128][32]bf16

  const int tid = threadIdx.x;
  const int w = tid >> 6;
  const int lane = tid & 63;
  const int lrow = lane & 15;
  const int hi = lane >> 4;
  const int lk8 = hi * 8;
  // qt swizzle: each CU's 4 co-resident blocks (stride-256 ids) get qt spread
  // {x, x+4, x+8, x+12} -> per-CU iter sums within [56,80].
  const int qt = ((int)blockIdx.x + 4 * (int)blockIdx.z +
                  8 * ((int)blockIdx.y >> 4)) & 15;
  const int hq = blockIdx.y;
  const int b = blockIdx.z;
  const int hkv = hq >> 2;
  const int q0 = qt * kQT;
  const int nk = 2 * (qt + 1);

  const char* Kh = (const char*)(Kp + ((size_t)b * 8 + hkv) * 1024 * 128);
  const char* Vh = (const char*)(Vp + ((size_t)b * 8 + hkv) * 128 * 1024);

#define STAGE32(k0_, dstbuf_)                                                 \
  {                                                                           \
    char* Kd = KV[dstbuf_];                                                   \
    _Pragma("unroll") for (int ii = 0; ii < 2; ++ii) {                        \
      int i = w * 2 + ii;                                                     \
      int row = i * 4 + hi;                                                   \
      int srcb = ((k0_) + row) * 256 + (((lane & 15) * 16) ^ ((row & 7) << 4)); \
      gload16(Kh + srcb, Kd + i * 1024);                                      \
    }                                                                         \
    _Pragma("unroll") for (int ii = 0; ii < 2; ++ii) {                        \
      int i = w * 2 + ii;                                                     \
      int vrow = i * 16 + (lane >> 2);                                        \
      int srcb = vrow * 2048 + (k0_) * 2 +                                    \
                 (((lane & 3) * 16) ^ (((vrow >> 1) & 3) << 4));              \
      gload16(Vh + srcb, Kd + 8192 + i * 1024);                               \
    }                                                                         \
  }

  // ---- Q loads first (so their waits don't drain the stage queue) ----
  const int pos = q0 + w * 16 + lrow;
  const float* qrow = q + ((size_t)b * 1024 + pos) * 4096 + hq * kD;
  const float2* tp = tab + (size_t)pos * 64;
  float4 x1a0 = *(const float4*)&qrow[lk8];
  float4 x1b0 = *(const float4*)&qrow[lk8 + 4];
  float4 x2a0 = *(const float4*)&qrow[lk8 + 64];
  float4 x2b0 = *(const float4*)&qrow[lk8 + 68];
  float4 x1a1 = *(const float4*)&qrow[32 + lk8];
  float4 x1b1 = *(const float4*)&qrow[32 + lk8 + 4];
  float4 x2a1 = *(const float4*)&qrow[32 + lk8 + 64];
  float4 x2b1 = *(const float4*)&qrow[32 + lk8 + 68];
  float4 ta0 = *(const float4*)&tp[lk8];
  float4 tb0 = *(const float4*)&tp[lk8 + 2];
  float4 tc0 = *(const float4*)&tp[lk8 + 4];
  float4 td0 = *(const float4*)&tp[lk8 + 6];
  float4 ta1 = *(const float4*)&tp[32 + lk8];
  float4 tb1 = *(const float4*)&tp[32 + lk8 + 2];
  float4 tc1 = *(const float4*)&tp[32 + lk8 + 4];
  float4 td1 = *(const float4*)&tp[32 + lk8 + 6];

  STAGE32(0, 0);  // prologue stage, latency hidden under RoPE math below

  // ---- Q fragments: RoPE in registers. qf[d] = Q[q][d*32+hi*8 .. +7] ----
  bf16x8 qf[4];
  {
    bf16x8 lo, hb;
    lo[0] = f2bf((x1a0.x * ta0.x - x2a0.x * ta0.y) * kScale);
    hb[0] = f2bf((x1a0.x * ta0.y + x2a0.x * ta0.x) * kScale);
    lo[1] = f2bf((x1a0.y * ta0.z - x2a0.y * ta0.w) * kScale);
    hb[1] = f2bf((x1a0.y * ta0.w + x2a0.y * ta0.z) * kScale);
    lo[2] = f2bf((x1a0.z * tb0.x - x2a0.z * tb0.y) * kScale);
    hb[2] = f2bf((x1a0.z * tb0.y + x2a0.z * tb0.x) * kScale);
    lo[3] = f2bf((x1a0.w * tb0.z - x2a0.w * tb0.w) * kScale);
    hb[3] = f2bf((x1a0.w * tb0.w + x2a0.w * tb0.z) * kScale);
    lo[4] = f2bf((x1b0.x * tc0.x - x2b0.x * tc0.y) * kScale);
    hb[4] = f2bf((x1b0.x * tc0.y + x2b0.x * tc0.x) * kScale);
    lo[5] = f2bf((x1b0.y * tc0.z - x2b0.y * tc0.w) * kScale);
    hb[5] = f2bf((x1b0.y * tc0.w + x2b0.y * tc0.z) * kScale);
    lo[6] = f2bf((x1b0.z * td0.x - x2b0.z * td0.y) * kScale);
    hb[6] = f2bf((x1b0.z * td0.y + x2b0.z * td0.x) * kScale);
    lo[7] = f2bf((x1b0.w * td0.z - x2b0.w * td0.w) * kScale);
    hb[7] = f2bf((x1b0.w * td0.w + x2b0.w * td0.z) * kScale);
    qf[0] = lo; qf[2] = hb;
    lo[0] = f2bf((x1a1.x * ta1.x - x2a1.x * ta1.y) * kScale);
    hb[0] = f2bf((x1a1.x * ta1.y + x2a1.x * ta1.x) * kScale);
    lo[1] = f2bf((x1a1.y * ta1.z - x2a1.y * ta1.w) * kScale);
    hb[1] = f2bf((x1a1.y * ta1.w + x2a1.y * ta1.z) * kScale);
    lo[2] = f2bf((x1a1.z * tb1.x - x2a1.z * tb1.y) * kScale);
    hb[2] = f2bf((x1a1.z * tb1.y + x2a1.z * tb1.x) * kScale);
    lo[3] = f2bf((x1a1.w * tb1.z - x2a1.w * tb1.w) * kScale);
    hb[3] = f2bf((x1a1.w * tb1.w + x2a1.w * tb1.z) * kScale);
    lo[4] = f2bf((x1b1.x * tc1.x - x2b1.x * tc1.y) * kScale);
    hb[4] = f2bf((x1b1.x * tc1.y + x2b1.x * tc1.x) * kScale);
    lo[5] = f2bf((x1b1.y * tc1.z - x2b1.y * tc1.w) * kScale);
    hb[5] = f2bf((x1b1.y * tc1.w + x2b1.y * tc1.z) * kScale);
    lo[6] = f2bf((x1b1.z * td1.x - x2b1.z * td1.y) * kScale);
    hb[6] = f2bf((x1b1.z * td1.y + x2b1.z * td1.x) * kScale);
    lo[7] = f2bf((x1b1.w * td1.z - x2b1.w * td1.w) * kScale);
    hb[7] = f2bf((x1b1.w * td1.w + x2b1.w * td1.z) * kScale);
    qf[1] = lo; qf[3] = hb;
  }

  float m = -3e38f, l = 0.f;
  f32x4 acc[8];
#pragma unroll
  for (int dt = 0; dt < 8; ++dt) acc[dt] = f32x4{0.f, 0.f, 0.f, 0.f};

  const int srcA = lrow + 32 * (hi & 1);  // P-redistribution source lanes
  const int srcB = srcA + 16;
  const int c1 = hi >> 1;

  int buf = 0;
  for (int t = 0; t < nk; ++t) {
    const int k0 = t * kKT;
    if (t < nk - 1) {
      STAGE32((t + 1) * kKT, buf ^ 1);
      VMCNT(4);   // tile-t loads done; tile-(t+1)'s 4 stay in flight
    } else {
      VMCNT(0);
    }
    __builtin_amdgcn_sched_barrier(0);
    __builtin_amdgcn_s_barrier();
    __builtin_amdgcn_sched_barrier(0);

    const char* KsB = KV[buf];
    const char* VtB = KV[buf] + 8192;

    // ---- QK^T swapped: sc[ct] = K_tile(ct) * Q  -> P[key][q] layout ----
    f32x4 sc[2];
    __builtin_amdgcn_s_setprio(1);
#pragma unroll
    for (int ct = 0; ct < 2; ++ct) {
      sc[ct] = f32x4{0.f, 0.f, 0.f, 0.f};
      int kr = ct * 16 + lrow;
#pragma unroll
      for (int d = 0; d < 4; ++d) {
        bf16x8 kf = *(const bf16x8*)(KsB + kr * 256 +
                                     ((d * 64 + hi * 16) ^ ((lrow & 7) << 4)));
        sc[ct] = __builtin_amdgcn_mfma_f32_16x16x32_bf16(kf, qf[d], sc[ct], 0, 0, 0);
      }
    }
    __builtin_amdgcn_s_setprio(0);

    // ---- causal mask (last two k-tiles only) ----
    if (t >= nk - 2) {
      int qg = q0 + w * 16 + lrow;
#pragma unroll
      for (int ct = 0; ct < 2; ++ct)
#pragma unroll
        for (int r = 0; r < 4; ++r)
          if (k0 + ct * 16 + hi * 4 + r > qg) sc[ct][r] = -3e38f;
    }

    // ---- in-register online softmax (lane owns q-row lrow, 8 keys) ----
    float tv = fmaxf(fmaxf(fmaxf(sc[0][0], sc[0][1]), fmaxf(sc[0][2], sc[0][3])),
                     fmaxf(fmaxf(sc[1][0], sc[1][1]), fmaxf(sc[1][2], sc[1][3])));
    tv = fmaxf(tv, __shfl_xor(tv, 16));
    tv = fmaxf(tv, __shfl_xor(tv, 32));
    if (!__all(tv <= m + 8.f)) {   // defer-max THR=8
      float mn = fmaxf(m, tv);
      float al = exp2f((m - mn) * kLog2e);
      m = mn;
      l *= al;
      float alq[4];
#pragma unroll
      for (int r = 0; r < 4; ++r) alq[r] = __shfl(al, hi * 4 + r);
#pragma unroll
      for (int dt = 0; dt < 8; ++dt)
#pragma unroll
        for (int r = 0; r < 4; ++r) acc[dt][r] *= alq[r];
    }
    float p00 = exp2f((sc[0][0] - m) * kLog2e);
    float p01 = exp2f((sc[0][1] - m) * kLog2e);
    float p02 = exp2f((sc[0][2] - m) * kLog2e);
    float p03 = exp2f((sc[0][3] - m) * kLog2e);
    float p10 = exp2f((sc[1][0] - m) * kLog2e);
    float p11 = exp2f((sc[1][1] - m) * kLog2e);
    float p12 = exp2f((sc[1][2] - m) * kLog2e);
    float p13 = exp2f((sc[1][3] - m) * kLog2e);
    float rs = ((p00 + p01) + (p02 + p03)) + ((p10 + p11) + (p12 + p13));
    rs += __shfl_xor(rs, 16);
    rs += __shfl_xor(rs, 32);
    l += rs;

    // ---- P -> PV A-fragment, in registers (pack + shfl web) ----
    unsigned u00 = pkbf(p00, p01), u01 = pkbf(p02, p03);
    unsigned u10 = pkbf(p10, p11), u11 = pkbf(p12, p13);
    unsigned A0 = (unsigned)__shfl((int)u00, srcA);
    unsigned A0b = (unsigned)__shfl((int)u10, srcA);
    unsigned A1 = (unsigned)__shfl((int)u01, srcA);
    unsigned A1b = (unsigned)__shfl((int)u11, srcA);
    unsigned B0 = (unsigned)__shfl((int)u00, srcB);
    unsigned B0b = (unsigned)__shfl((int)u10, srcB);
    unsigned B1 = (unsigned)__shfl((int)u01, srcB);
    unsigned B1b = (unsigned)__shfl((int)u11, srcB);
    union { unsigned u[4]; bf16x8 v; } pc;
    pc.u[0] = c1 ? A0b : A0;
    pc.u[1] = c1 ? A1b : A1;
    pc.u[2] = c1 ? B0b : B0;
    pc.u[3] = c1 ? B1b : B1;
    bf16x8 pa = pc.v;

    // ---- PV: acc[dt] += P * V ----
    __builtin_amdgcn_s_setprio(1);
#pragma unroll
    for (int dt = 0; dt < 8; ++dt) {
      int rv = dt * 16 + lrow;
      bf16x8 vf = *(const bf16x8*)(VtB + rv * 64 +
                                   ((hi * 16) ^ (((rv >> 1) & 3) << 4)));
      acc[dt] = __builtin_amdgcn_mfma_f32_16x16x32_bf16(pa, vf, acc[dt], 0, 0, 0);
    }
    __builtin_amdgcn_s_setprio(0);
    __builtin_amdgcn_sched_barrier(0);
    __builtin_amdgcn_s_barrier();   // all reads of KV[buf] done before overwrite
    __builtin_amdgcn_sched_barrier(0);
    buf ^= 1;
  }

  // ---- epilogue: out = acc / l  (l lives at lane q; acc rows q=hi*4+r) ----
  float il[4];
#pragma unroll
  for (int r = 0; r < 4; ++r) il[r] = 1.f / __shfl(l, hi * 4 + r);
  float* ob = out + ((size_t)b * kS + q0 + w * 16) * 4096 + hq * kD;
#pragma unroll
  for (int dt = 0; dt < 8; ++dt)
#pragma unroll
    for (int r = 0; r < 4; ++r)
      ob[(hi * 4 + r) * 4096 + dt * 16 + lrow] = acc[dt][r] * il[r];
#undef STAGE32
}

// ---------------- fallback (small-ws path) ----------------
template <bool USE_TAB>
__global__ __launch_bounds__(256) void attn_k(
    const float* __restrict__ q, const float* __restrict__ k,
    const float* __restrict__ v, const float2* __restrict__ tab,
    float* __restrict__ out) {
  __shared__ short Ksf[64][kKPad];
  __shared__ short Vtf[kD][kVPad];
  __shared__ short Qbuf[kQT * kKPad];
  const int tid = threadIdx.x;
  const int w = tid >> 6;
  const int lane = tid & 63;
  const int lrow = lane & 15;
  const int lk8 = (lane >> 4) * 8;
  const int qt = (int)gridDim.x - 1 - (int)blockIdx.x;
  const int hq = blockIdx.y;
  const int b = blockIdx.z;
  const int hkv = hq >> 2;
  const int q0 = qt * kQT;
  const float* qb = q + (size_t)b * kS * 4096 + hq * kD;
  const float* kb = k + (size_t)b * kS * 1024 + hkv * kD;
  const float* vb = v + (size_t)b * kS * 1024 + hkv * kD;
#pragma unroll
  for (int it = 0; it < 16; ++it) {
    int pi = tid + it * 256;
    int row = pi >> 6, j = pi & 63;
    int pos = q0 + row;
    float x1 = qb[(size_t)pos * 4096 + j];
    float x2 = qb[(size_t)pos * 4096 + j + 64];
    float c, s;
    if (USE_TAB) { float2 t2 = tab[(pos << 6) + j]; c = t2.x; s = t2.y; }
    else { float ang = (float)pos * __expf(-(float)j * kFreqC); __sincosf(ang, &s, &c); }
    Qbuf[row * kKPad + j]      = f2bf((x1 * c - x2 * s) * kScale);
    Qbuf[row * kKPad + j + 64] = f2bf((x1 * s + x2 * c) * kScale);
  }
  __syncthreads();
  bf16x8 qf[4];
#pragma unroll
  for (int d = 0; d < 4; ++d)
    qf[d] = *(const bf16x8*)&Qbuf[(w * 16 + lrow) * kKPad + d * 32 + lk8];
  __syncthreads();
  short* myP = Qbuf + w * 16 * kVPad;
  float mS[4] = {-3e38f, -3e38f, -3e38f, -3e38f};
  float lS[4] = {0.f, 0.f, 0.f, 0.f};
  f32x4 acc[8];
#pragma unroll
  for (int dt = 0; dt < 8; ++dt) acc[dt] = f32x4{0.f, 0.f, 0.f, 0.f};
  for (int kt = 0; kt <= qt; ++kt) {
    const int k0 = kt * 64;
#pragma unroll
    for (int it = 0; it < 16; ++it) {
      int pi = tid + it * 256;
      int row = pi >> 6, j = pi & 63;
      int pos = k0 + row;
      float x1 = kb[(size_t)pos * 1024 + j];
      float x2 = kb[(size_t)pos * 1024 + j + 64];
      float c, s;
      if (USE_TAB) { float2 t2 = tab[(pos << 6) + j]; c = t2.x; s = t2.y; }
      else { float ang = (float)pos * __expf(-(float)j * kFreqC); __sincosf(ang, &s, &c); }
      Ksf[row][j]      = f2bf(x1 * c - x2 * s);
      Ksf[row][j + 64] = f2bf(x1 * s + x2 * c);
    }
#pragma unroll
    for (int it = 0; it < 8; ++it) {
      int f = (tid + it * 256) * 4;
      int row = f >> 7, col = f & 127;
      const float4 v4 = *(const float4*)(vb + (size_t)(k0 + row) * 1024 + col);
      Vtf[col + 0][row] = f2bf(v4.x);
      Vtf[col + 1][row] = f2bf(v4.y);
      Vtf[col + 2][row] = f2bf(v4.z);
      Vtf[col + 3][row] = f2bf(v4.w);
    }
    __syncthreads();
    f32x4 sc[4];
#pragma unroll
    for (int ct = 0; ct < 4; ++ct) {
      sc[ct] = f32x4{0.f, 0.f, 0.f, 0.f};
#pragma unroll
      for (int d = 0; d < 4; ++d) {
        bf16x8 kf = *(const bf16x8*)&Ksf[ct * 16 + lrow][d * 32 + lk8];
        sc[ct] = __builtin_amdgcn_mfma_f32_16x16x32_bf16(qf[d], kf, sc[ct], 0, 0, 0);
      }
    }
    if (kt == qt) {
#pragma unroll
      for (int ct = 0; ct < 4; ++ct) {
        int col = ct * 16 + lrow;
#pragma unroll
        for (int r = 0; r < 4; ++r) {
          int row = w * 16 + (lane >> 4) * 4 + r;
          if (col > row) sc[ct][r] = -3e38f;
        }
      }
    }
#pragma unroll
    for (int r = 0; r < 4; ++r) {
      float t = fmaxf(fmaxf(sc[0][r], sc[1][r]), fmaxf(sc[2][r], sc[3][r]));
      t = fmaxf(t, __shfl_xor(t, 1));
      t = fmaxf(t, __shfl_xor(t, 2));
      t = fmaxf(t, __shfl_xor(t, 4));
      t = fmaxf(t, __shfl_xor(t, 8));
      float mn = fmaxf(mS[r], t);
      float al = exp2f((mS[r] - mn) * kLog2e);
      float rs = 0.f;
#pragma unroll
      for (int ct = 0; ct < 4; ++ct) {
        float p = exp2f((sc[ct][r] - mn) * kLog2e);
        sc[ct][r] = p;
        rs += p;
      }
      rs += __shfl_xor(rs, 1);
      rs += __shfl_xor(rs, 2);
      rs += __shfl_xor(rs, 4);
      rs += __shfl_xor(rs, 8);
      lS[r] = lS[r] * al + rs;
      mS[r] = mn;
#pragma unroll
      for (int dt = 0; dt < 8; ++dt) acc[dt][r] *= al;
    }
#pragma unroll
    for (int ct = 0; ct < 4; ++ct)
#pragma unroll
      for (int r = 0; r < 4; ++r)
        myP[((lane >> 4) * 4 + r) * kVPad + ct * 16 + lrow] = f2bf(sc[ct][r]);
#pragma unroll
    for (int ks = 0; ks < 2; ++ks) {
      bf16x8 pf = *(const bf16x8*)&myP[lrow * kVPad + ks * 32 + lk8];
#pragma unroll
      for (int dt = 0; dt < 8; ++dt) {
        bf16x8 vf = *(const bf16x8*)&Vtf[dt * 16 + lrow][ks * 32 + lk8];
        acc[dt] = __builtin_amdgcn_mfma_f32_16x16x32_bf16(pf, vf, acc[dt], 0, 0, 0);
      }
    }
    __syncthreads();
  }
  float il[4];
#pragma unroll
  for (int r = 0; r < 4; ++r) il[r] = 1.f / lS[r];
  float* ob = out + ((size_t)b * kS + q0 + w * 16) * 4096 + hq * kD;
#pragma unroll
  for (int dt = 0; dt < 8; ++dt)
#pragma unroll
    for (int r = 0; r < 4; ++r)
      ob[((lane >> 4) * 4 + r) * 4096 + dt * 16 + lrow] = acc[dt][r] * il[r];
}

extern "C" void kernel_launch(void* const* d_in, const int* in_sizes, int n_in,
                              void* d_out, int out_size, void* d_ws, size_t ws_size,
                              hipStream_t stream) {
  const float* q = (const float*)d_in[0];
  const float* k = (const float*)d_in[1];
  const float* v = (const float*)d_in[2];
  float* out = (float*)d_out;

  if (ws_size >= kWsNeed) {
    float2* tab = (float2*)((char*)d_ws + kTabOff);
    short* Kp = (short*)((char*)d_ws + kKOff);
    short* Vp = (short*)((char*)d_ws + kVOff);
    rope_table_k<<<256, 256, 0, stream>>>(tab);
    prep_k<<<1536, 256, 0, stream>>>(k, v, tab, Kp, Vp);
    dim3 grid(kNT, 32, kB);  // (16, 32, 2) -> 1024 blocks, all co-resident
    attn_swp_k<<<grid, 256, 0, stream>>>(q, Kp, Vp, tab, out);
  } else if (ws_size >= 512 * 1024) {
    float2* tab = (float2*)d_ws;
    rope_table_k<<<256, 256, 0, stream>>>(tab);
    dim3 grid(kNT, 32, kB);
    attn_k<true><<<grid, 256, 0, stream>>>(q, k, v, tab, out);
  } else {
    dim3 grid(kNT, 32, kB);
    attn_k<false><<<grid, 256, 0, stream>>>(q, k, v, nullptr, out);
  }
}

// Round 8
// 64.151 us; speedup vs baseline: 2.7298x; 1.1017x over previous
//
#include <hip/hip_runtime.h>
#include <math.h>

typedef __attribute__((ext_vector_type(4))) float f32x4;
typedef __attribute__((ext_vector_type(16))) float f32x16;
typedef __attribute__((ext_vector_type(8))) short bf16x8;

namespace {
constexpr int kB = 2;
constexpr int kS = 1024;
constexpr int kD = 128;
constexpr float kScale = 0.08838834764831845f;   // 1/sqrt(128)
constexpr float kLog2e = 1.4426950408889634f;
constexpr float kFreqC = 0.20503692777194262f;   // ln(500000)/64
constexpr int kKPad = 136;  // fallback kernel pads
constexpr int kVPad = 72;

// workspace layout (bytes)
constexpr size_t kTabOff = 0;                       // float2[1024*64] = 512 KB
constexpr size_t kKOff = 512 * 1024;                // bf16 [2][8][1024][128]
constexpr size_t kVOff = kKOff + 4194304;           // bf16 [2][8][128][1024]
constexpr size_t kWsNeed = kVOff + 4194304;         // ~8.9 MB
}

#define VMCNT(n) asm volatile("s_waitcnt vmcnt(" #n ")" ::: "memory")

__device__ inline short f2bf(float f) {  // RNE float->bf16
  union { float f; unsigned u; } c{f};
  unsigned r = c.u + 0x7fffu + ((c.u >> 16) & 1u);
  return (short)(r >> 16);
}

__device__ inline unsigned pkbf(float a, float b) {  // (bf16(b)<<16)|bf16(a)
  unsigned r;
  asm("v_cvt_pk_bf16_f32 %0, %1, %2" : "=v"(r) : "v"(a), "v"(b));
  return r;
}

__device__ inline void gload16(const void* g, void* l) {
  __builtin_amdgcn_global_load_lds(
      (const __attribute__((address_space(1))) void*)g,
      (__attribute__((address_space(3))) void*)l, 16, 0, 0);
}

// tab[pos*64 + j] = (cos(pos*f_j), sin(pos*f_j))
__global__ __launch_bounds__(256) void rope_table_k(float2* __restrict__ tab) {
  int t = blockIdx.x * 256 + threadIdx.x;  // 1024*64
  int pos = t >> 6, j = t & 63;
  float ang = (float)pos * expf(-(float)j * kFreqC);
  float sn, cs;
  sincosf(ang, &sn, &cs);
  tab[t] = make_float2(cs, sn);
}

// Fused prepass: blocks [0,1024) RoPE K -> bf16 [b][h][s][d];
// blocks [1024,1536) transpose V -> [b][hkv][d][s] bf16.
__global__ __launch_bounds__(256) void prep_k(
    const float* __restrict__ k, const float* __restrict__ v,
    const float2* __restrict__ tab, short* __restrict__ Kp,
    short* __restrict__ Vp) {
  __shared__ float Tl[64][68];
  int bid = blockIdx.x;
  if (bid < 1024) {
    int t2 = bid * 256 + threadIdx.x;  // 262144
    int j = (t2 & 15) * 4;
    int h = (t2 >> 4) & 7;
    int s = (t2 >> 7) & 1023;
    int b = t2 >> 17;
    size_t sidx = ((size_t)b * 1024 + s) * 1024 + h * 128 + j;
    size_t didx = (((size_t)b * 8 + h) * 1024 + s) * 128 + j;
    float4 x1 = *(const float4*)&k[sidx];
    float4 x2 = *(const float4*)&k[sidx + 64];
    float4 t0 = *(const float4*)&tab[s * 64 + j];      // c0 s0 c1 s1
    float4 t1 = *(const float4*)&tab[s * 64 + j + 2];  // c2 s2 c3 s3
    short4 y1, y2;
    y1.x = f2bf(x1.x * t0.x - x2.x * t0.y);
    y2.x = f2bf(x1.x * t0.y + x2.x * t0.x);
    y1.y = f2bf(x1.y * t0.z - x2.y * t0.w);
    y2.y = f2bf(x1.y * t0.w + x2.y * t0.z);
    y1.z = f2bf(x1.z * t1.x - x2.z * t1.y);
    y2.z = f2bf(x1.z * t1.y + x2.z * t1.x);
    y1.w = f2bf(x1.w * t1.z - x2.w * t1.w);
    y2.w = f2bf(x1.w * t1.w + x2.w * t1.z);
    *(short4*)&Kp[didx] = y1;
    *(short4*)&Kp[didx + 64] = y2;
  } else {
    int blk = bid - 1024;
    int bh = blk >> 5;            // 0..15 = b*8+h
    int rem = blk & 31;
    int s0 = (rem >> 1) * 64;
    int d0 = (rem & 1) * 64;
    int t = threadIdx.x;
#pragma unroll
    for (int i = 0; i < 4; ++i) {
      int srow = i * 16 + (t >> 4);
      int scol = (t & 15) * 4;
      float4 x = *(const float4*)&v[((size_t)(bh >> 3) * 1024 + s0 + srow) * 1024 +
                                    (bh & 7) * 128 + d0 + scol];
      *(float4*)&Tl[srow][scol] = x;
    }
    __syncthreads();
#pragma unroll
    for (int i = 0; i < 4; ++i) {
      int drow = i * 16 + (t >> 4);
      int sq = (t & 15) * 4;
      short4 y;
      y.x = f2bf(Tl[sq + 0][drow]);
      y.y = f2bf(Tl[sq + 1][drow]);
      y.z = f2bf(Tl[sq + 2][drow]);
      y.w = f2bf(Tl[sq + 3][drow]);
      *(short4*)&Vp[((size_t)bh * 128 + d0 + drow) * 1024 + s0 + sq] = y;
    }
  }
}

// Main attention: 32x32x16 MFMA, 128-row q-tile (32/wave), KV=64 double-buffer
// via swizzled global_load_lds + counted vmcnt. Swapped QK^T -> per-lane P row;
// softmax in registers (1 cross-lane op); P->A-frag via cvt_pk + permlane32_swap.
__global__ __launch_bounds__(256, 2) void attn32_k(
    const float* __restrict__ q, const short* __restrict__ Kp,
    const short* __restrict__ Vp, const float2* __restrict__ tab,
    float* __restrict__ out) {
  __shared__ char KV[2][32768];  // per buf: K [64][128]bf16 | Vt [128][64]bf16

  const int tid = threadIdx.x;
  const int w = tid >> 6;
  const int lane = tid & 63;
  const int l31 = lane & 31;
  const int hi5 = lane >> 5;
  // complementary-qt co-residency: blocks differing only in bz share a CU slot
  // and get qt summing to 7 -> uniform per-CU work.
  const int f = ((int)blockIdx.x + (int)blockIdx.y) & 7;
  const int b = blockIdx.z;
  const int qt = b ? (7 - f) : f;
  const int hq = blockIdx.y;
  const int hkv = hq >> 2;
  const int q0 = qt * 128;
  const int nk = 2 * (qt + 1);

  const char* Kh = (const char*)(Kp + ((size_t)b * 8 + hkv) * 1024 * 128);
  const char* Vh = (const char*)(Vp + ((size_t)b * 8 + hkv) * 128 * 1024);

#define STAGE(k0_, bufi_)                                                     \
  {                                                                           \
    char* Kd = KV[bufi_];                                                     \
    char* Vd = KV[bufi_] + 16384;                                             \
    _Pragma("unroll") for (int ii = 0; ii < 4; ++ii) {                        \
      int i = w * 4 + ii;                                                     \
      int row = i * 4 + (lane >> 4);                                          \
      int srcb = ((k0_) + row) * 256 + (((lane & 15) * 16) ^ ((row & 7) << 4)); \
      gload16(Kh + srcb, Kd + i * 1024);                                      \
    }                                                                         \
    _Pragma("unroll") for (int ii = 0; ii < 4; ++ii) {                        \
      int i = w * 4 + ii;                                                     \
      int d = i * 8 + (lane >> 3);                                            \
      int srcb = d * 2048 + (k0_) * 2 + (((lane & 7) * 16) ^ ((d & 7) << 4)); \
      gload16(Vh + srcb, Vd + i * 1024);                                      \
    }                                                                         \
  }

  STAGE(0, 0);  // prologue stage; latency hidden under Q RoPE below

  // ---- Q B-fragments: RoPE in registers. qB[c] = Q[q=l31][16c+8*hi5 .. +7] ----
  const int qrow = q0 + w * 32 + l31;
  const float* qp = q + ((size_t)b * 1024 + qrow) * 4096 + hq * 128;
  const float2* tp = tab + (size_t)qrow * 64;
  bf16x8 qB[8];
#pragma unroll
  for (int g = 0; g < 4; ++g) {
    int jb = g * 16 + hi5 * 8;
    float4 x1a = *(const float4*)&qp[jb];
    float4 x1b = *(const float4*)&qp[jb + 4];
    float4 x2a = *(const float4*)&qp[jb + 64];
    float4 x2b = *(const float4*)&qp[jb + 68];
    float4 t0 = *(const float4*)&tp[jb];
    float4 t1 = *(const float4*)&tp[jb + 2];
    float4 t2 = *(const float4*)&tp[jb + 4];
    float4 t3 = *(const float4*)&tp[jb + 6];
    float lo[8], hb[8];
    lo[0] = (x1a.x * t0.x - x2a.x * t0.y) * kScale;
    hb[0] = (x1a.x * t0.y + x2a.x * t0.x) * kScale;
    lo[1] = (x1a.y * t0.z - x2a.y * t0.w) * kScale;
    hb[1] = (x1a.y * t0.w + x2a.y * t0.z) * kScale;
    lo[2] = (x1a.z * t1.x - x2a.z * t1.y) * kScale;
    hb[2] = (x1a.z * t1.y + x2a.z * t1.x) * kScale;
    lo[3] = (x1a.w * t1.z - x2a.w * t1.w) * kScale;
    hb[3] = (x1a.w * t1.w + x2a.w * t1.z) * kScale;
    lo[4] = (x1b.x * t2.x - x2b.x * t2.y) * kScale;
    hb[4] = (x1b.x * t2.y + x2b.x * t2.x) * kScale;
    lo[5] = (x1b.y * t2.z - x2b.y * t2.w) * kScale;
    hb[5] = (x1b.y * t2.w + x2b.y * t2.z) * kScale;
    lo[6] = (x1b.z * t3.x - x2b.z * t3.y) * kScale;
    hb[6] = (x1b.z * t3.y + x2b.z * t3.x) * kScale;
    lo[7] = (x1b.w * t3.z - x2b.w * t3.w) * kScale;
    hb[7] = (x1b.w * t3.w + x2b.w * t3.z) * kScale;
    union { unsigned u[4]; bf16x8 v; } A, C;
#pragma unroll
    for (int ww = 0; ww < 4; ++ww) {
      A.u[ww] = pkbf(lo[2 * ww], lo[2 * ww + 1]);
      C.u[ww] = pkbf(hb[2 * ww], hb[2 * ww + 1]);
    }
    qB[g] = A.v;
    qB[g + 4] = C.v;
  }

  float m = -3e38f, l = 0.f;
  f32x16 acc[4];
#pragma unroll
  for (int dt = 0; dt < 4; ++dt)
#pragma unroll
    for (int e = 0; e < 16; ++e) acc[dt][e] = 0.f;

  int buf = 0;
  for (int t = 0; t < nk; ++t) {
    if (t < nk - 1) {
      STAGE((t + 1) * 64, buf ^ 1);
      VMCNT(8);   // tile-t loads done; tile-(t+1)'s 8 stay in flight
    } else {
      VMCNT(0);
    }
    __builtin_amdgcn_sched_barrier(0);
    __builtin_amdgcn_s_barrier();
    __builtin_amdgcn_sched_barrier(0);

    const char* Ks = KV[buf];
    const char* Vt = KV[buf] + 16384;

    // ---- QK^T swapped: sc0/sc1 = K(keys 0-31 / 32-63) x Q -> P[key][q] ----
    f32x16 sc0, sc1;
#pragma unroll
    for (int e = 0; e < 16; ++e) { sc0[e] = 0.f; sc1[e] = 0.f; }
    const int kswz = (l31 & 7) << 4;
    __builtin_amdgcn_s_setprio(1);
#pragma unroll
    for (int c = 0; c < 8; ++c) {
      int off = c * 32 + hi5 * 16;
      bf16x8 k0f = *(const bf16x8*)(Ks + l31 * 256 + (off ^ kswz));
      bf16x8 k1f = *(const bf16x8*)(Ks + (32 + l31) * 256 + (off ^ kswz));
      sc0 = __builtin_amdgcn_mfma_f32_32x32x16_bf16(k0f, qB[c], sc0, 0, 0, 0);
      sc1 = __builtin_amdgcn_mfma_f32_32x32x16_bf16(k1f, qB[c], sc1, 0, 0, 0);
    }
    __builtin_amdgcn_s_setprio(0);

    // ---- causal mask (wave-uniform predicate) ----
    if (64 * (t + 1) > q0 + 32 * w) {
      int kb = t * 64 + hi5 * 4;
#pragma unroll
      for (int r = 0; r < 16; ++r) {
        int off = (r & 3) + 8 * (r >> 2);
        if (kb + off > qrow) sc0[r] = -3e38f;
        if (kb + 32 + off > qrow) sc1[r] = -3e38f;
      }
    }

    // ---- in-register online softmax (lane pair {l, l^32} owns q-row l31) ----
    float tv = -3e38f;
#pragma unroll
    for (int r = 0; r < 16; ++r) tv = fmaxf(tv, fmaxf(sc0[r], sc1[r]));
    tv = fmaxf(tv, __shfl_xor(tv, 32));
    if (!__all(tv <= m + 8.f)) {   // defer-max THR=8
      float mn = fmaxf(m, tv);
      float al = exp2f((m - mn) * kLog2e);
      m = mn;
      l *= al;
#pragma unroll
      for (int r = 0; r < 16; ++r) {
        float alr = __shfl(al, (r & 3) + 8 * (r >> 2) + 4 * hi5);
        acc[0][r] *= alr;
        acc[1][r] *= alr;
        acc[2][r] *= alr;
        acc[3][r] *= alr;
      }
    }
    float rs = 0.f;
#pragma unroll
    for (int r = 0; r < 16; ++r) {
      sc0[r] = exp2f((sc0[r] - m) * kLog2e);
      sc1[r] = exp2f((sc1[r] - m) * kLog2e);
      rs += sc0[r] + sc1[r];
    }
    rs += __shfl_xor(rs, 32);
    l += rs;

    // ---- P -> A-frag (cvt_pk + permlane32_swap) fused with PV MFMA ----
    __builtin_amdgcn_s_setprio(1);
#define PV_CHUNK(S, CI)                                                       \
    {                                                                         \
      unsigned p0 = pkbf(S[8 * ((CI) & 1) + 0], S[8 * ((CI) & 1) + 1]);       \
      unsigned p1 = pkbf(S[8 * ((CI) & 1) + 2], S[8 * ((CI) & 1) + 3]);       \
      unsigned p2 = pkbf(S[8 * ((CI) & 1) + 4], S[8 * ((CI) & 1) + 5]);       \
      unsigned p3 = pkbf(S[8 * ((CI) & 1) + 6], S[8 * ((CI) & 1) + 7]);       \
      asm("v_permlane32_swap_b32 %0, %1" : "+v"(p0), "+v"(p2));               \
      asm("v_permlane32_swap_b32 %0, %1" : "+v"(p1), "+v"(p3));               \
      union { unsigned u[4]; bf16x8 v; } pa;                                  \
      pa.u[0] = p0; pa.u[1] = p1; pa.u[2] = p2; pa.u[3] = p3;                 \
      int ko = (CI) * 32 + hi5 * 16;                                          \
      _Pragma("unroll") for (int dt = 0; dt < 4; ++dt) {                      \
        int d = dt * 32 + l31;                                                \
        bf16x8 vf = *(const bf16x8*)(Vt + d * 128 + (ko ^ ((d & 7) << 4)));   \
        acc[dt] =                                                             \
            __builtin_amdgcn_mfma_f32_32x32x16_bf16(pa.v, vf, acc[dt], 0, 0, 0); \
      }                                                                       \
    }
    PV_CHUNK(sc0, 0)
    PV_CHUNK(sc0, 1)
    PV_CHUNK(sc1, 2)
    PV_CHUNK(sc1, 3)
#undef PV_CHUNK
    __builtin_amdgcn_s_setprio(0);

    __builtin_amdgcn_sched_barrier(0);
    __builtin_amdgcn_s_barrier();   // all reads of KV[buf] done before overwrite
    __builtin_amdgcn_sched_barrier(0);
    buf ^= 1;
  }

  // ---- epilogue: out[q][d] = acc / l ----
  float linv = 1.f / l;
  const size_t obase = ((size_t)b * 1024 + q0 + w * 32) * 4096 + (size_t)hq * 128;
#pragma unroll
  for (int r = 0; r < 16; ++r) {
    int rq = (r & 3) + 8 * (r >> 2) + 4 * hi5;   // q row in [0,32)
    float ilr = __shfl(linv, rq);                // lane rq holds q=rq
    float* orow = out + obase + (size_t)rq * 4096 + l31;
    orow[0]  = acc[0][r] * ilr;
    orow[32] = acc[1][r] * ilr;
    orow[64] = acc[2][r] * ilr;
    orow[96] = acc[3][r] * ilr;
  }
#undef STAGE
}

// ---------------- fallback (small-ws path) ----------------
template <bool USE_TAB>
__global__ __launch_bounds__(256) void attn_k(
    const float* __restrict__ q, const float* __restrict__ k,
    const float* __restrict__ v, const float2* __restrict__ tab,
    float* __restrict__ out) {
  __shared__ short Ksf[64][kKPad];
  __shared__ short Vtf[kD][kVPad];
  __shared__ short Qbuf[64 * kKPad];
  const int tid = threadIdx.x;
  const int w = tid >> 6;
  const int lane = tid & 63;
  const int lrow = lane & 15;
  const int lk8 = (lane >> 4) * 8;
  const int qt = (int)gridDim.x - 1 - (int)blockIdx.x;
  const int hq = blockIdx.y;
  const int b = blockIdx.z;
  const int hkv = hq >> 2;
  const int q0 = qt * 64;
  const float* qb = q + (size_t)b * kS * 4096 + hq * kD;
  const float* kb = k + (size_t)b * kS * 1024 + hkv * kD;
  const float* vb = v + (size_t)b * kS * 1024 + hkv * kD;
#pragma unroll
  for (int it = 0; it < 16; ++it) {
    int pi = tid + it * 256;
    int row = pi >> 6, j = pi & 63;
    int pos = q0 + row;
    float x1 = qb[(size_t)pos * 4096 + j];
    float x2 = qb[(size_t)pos * 4096 + j + 64];
    float c, s;
    if (USE_TAB) { float2 t2 = tab[(pos << 6) + j]; c = t2.x; s = t2.y; }
    else { float ang = (float)pos * __expf(-(float)j * kFreqC); __sincosf(ang, &s, &c); }
    Qbuf[row * kKPad + j]      = f2bf((x1 * c - x2 * s) * kScale);
    Qbuf[row * kKPad + j + 64] = f2bf((x1 * s + x2 * c) * kScale);
  }
  __syncthreads();
  bf16x8 qf[4];
#pragma unroll
  for (int d = 0; d < 4; ++d)
    qf[d] = *(const bf16x8*)&Qbuf[(w * 16 + lrow) * kKPad + d * 32 + lk8];
  __syncthreads();
  short* myP = Qbuf + w * 16 * kVPad;
  float mS[4] = {-3e38f, -3e38f, -3e38f, -3e38f};
  float lS[4] = {0.f, 0.f, 0.f, 0.f};
  f32x4 acc[8];
#pragma unroll
  for (int dt = 0; dt < 8; ++dt) acc[dt] = f32x4{0.f, 0.f, 0.f, 0.f};
  for (int kt = 0; kt <= qt; ++kt) {
    const int k0 = kt * 64;
#pragma unroll
    for (int it = 0; it < 16; ++it) {
      int pi = tid + it * 256;
      int row = pi >> 6, j = pi & 63;
      int pos = k0 + row;
      float x1 = kb[(size_t)pos * 1024 + j];
      float x2 = kb[(size_t)pos * 1024 + j + 64];
      float c, s;
      if (USE_TAB) { float2 t2 = tab[(pos << 6) + j]; c = t2.x; s = t2.y; }
      else { float ang = (float)pos * __expf(-(float)j * kFreqC); __sincosf(ang, &s, &c); }
      Ksf[row][j]      = f2bf(x1 * c - x2 * s);
      Ksf[row][j + 64] = f2bf(x1 * s + x2 * c);
    }
#pragma unroll
    for (int it = 0; it < 8; ++it) {
      int f = (tid + it * 256) * 4;
      int row = f >> 7, col = f & 127;
      const float4 v4 = *(const float4*)(vb + (size_t)(k0 + row) * 1024 + col);
      Vtf[col + 0][row] = f2bf(v4.x);
      Vtf[col + 1][row] = f2bf(v4.y);
      Vtf[col + 2][row] = f2bf(v4.z);
      Vtf[col + 3][row] = f2bf(v4.w);
    }
    __syncthreads();
    f32x4 sc[4];
#pragma unroll
    for (int ct = 0; ct < 4; ++ct) {
      sc[ct] = f32x4{0.f, 0.f, 0.f, 0.f};
#pragma unroll
      for (int d = 0; d < 4; ++d) {
        bf16x8 kf = *(const bf16x8*)&Ksf[ct * 16 + lrow][d * 32 + lk8];
        sc[ct] = __builtin_amdgcn_mfma_f32_16x16x32_bf16(qf[d], kf, sc[ct], 0, 0, 0);
      }
    }
    if (kt == qt) {
#pragma unroll
      for (int ct = 0; ct < 4; ++ct) {
        int col = ct * 16 + lrow;
#pragma unroll
        for (int r = 0; r < 4; ++r) {
          int row = w * 16 + (lane >> 4) * 4 + r;
          if (col > row) sc[ct][r] = -3e38f;
        }
      }
    }
#pragma unroll
    for (int r = 0; r < 4; ++r) {
      float t = fmaxf(fmaxf(sc[0][r], sc[1][r]), fmaxf(sc[2][r], sc[3][r]));
      t = fmaxf(t, __shfl_xor(t, 1));
      t = fmaxf(t, __shfl_xor(t, 2));
      t = fmaxf(t, __shfl_xor(t, 4));
      t = fmaxf(t, __shfl_xor(t, 8));
      float mn = fmaxf(mS[r], t);
      float al = exp2f((mS[r] - mn) * kLog2e);
      float rs = 0.f;
#pragma unroll
      for (int ct = 0; ct < 4; ++ct) {
        float p = exp2f((sc[ct][r] - mn) * kLog2e);
        sc[ct][r] = p;
        rs += p;
      }
      rs += __shfl_xor(rs, 1);
      rs += __shfl_xor(rs, 2);
      rs += __shfl_xor(rs, 4);
      rs += __shfl_xor(rs, 8);
      lS[r] = lS[r] * al + rs;
      mS[r] = mn;
#pragma unroll
      for (int dt = 0; dt < 8; ++dt) acc[dt][r] *= al;
    }
#pragma unroll
    for (int ct = 0; ct < 4; ++ct)
#pragma unroll
      for (int r = 0; r < 4; ++r)
        myP[((lane >> 4) * 4 + r) * kVPad + ct * 16 + lrow] = f2bf(sc[ct][r]);
#pragma unroll
    for (int ks = 0; ks < 2; ++ks) {
      bf16x8 pf = *(const bf16x8*)&myP[lrow * kVPad + ks * 32 + lk8];
#pragma unroll
      for (int dt = 0; dt < 8; ++dt) {
        bf16x8 vf = *(const bf16x8*)&Vtf[dt * 16 + lrow][ks * 32 + lk8];
        acc[dt] = __builtin_amdgcn_mfma_f32_16x16x32_bf16(pf, vf, acc[dt], 0, 0, 0);
      }
    }
    __syncthreads();
  }
  float il[4];
#pragma unroll
  for (int r = 0; r < 4; ++r) il[r] = 1.f / lS[r];
  float* ob = out + ((size_t)b * kS + q0 + w * 16) * 4096 + hq * kD;
#pragma unroll
  for (int dt = 0; dt < 8; ++dt)
#pragma unroll
    for (int r = 0; r < 4; ++r)
      ob[((lane >> 4) * 4 + r) * 4096 + dt * 16 + lrow] = acc[dt][r] * il[r];
}

extern "C" void kernel_launch(void* const* d_in, const int* in_sizes, int n_in,
                              void* d_out, int out_size, void* d_ws, size_t ws_size,
                              hipStream_t stream) {
  const float* q = (const float*)d_in[0];
  const float* k = (const float*)d_in[1];
  const float* v = (const float*)d_in[2];
  float* out = (float*)d_out;

  if (ws_size >= kWsNeed) {
    float2* tab = (float2*)((char*)d_ws + kTabOff);
    short* Kp = (short*)((char*)d_ws + kKOff);
    short* Vp = (short*)((char*)d_ws + kVOff);
    rope_table_k<<<256, 256, 0, stream>>>(tab);
    prep_k<<<1536, 256, 0, stream>>>(k, v, tab, Kp, Vp);
    dim3 grid(8, 32, kB);  // 512 blocks = 2 per CU
    attn32_k<<<grid, 256, 0, stream>>>(q, Kp, Vp, tab, out);
  } else if (ws_size >= 512 * 1024) {
    float2* tab = (float2*)d_ws;
    rope_table_k<<<256, 256, 0, stream>>>(tab);
    dim3 grid(16, 32, kB);
    attn_k<true><<<grid, 256, 0, stream>>>(q, k, v, tab, out);
  } else {
    dim3 grid(16, 32, kB);
    attn_k<false><<<grid, 256, 0, stream>>>(q, k, v, nullptr, out);
  }
}